// Round 10
// baseline (238.368 us; speedup 1.0000x reference)
//
#include <hip/hip_runtime.h>

// out[r, i] = sum_{k=0..4} W[i,k] * x[r, i+k-2] + b[i], zero-padded at edges.
// B=8192 rows, C=4096 channels, K=5, fp32.
//
// R1-R4: compiler-scheduled direct loads, best ~76 us (loads sunk -> one
//   exposed latency/row). R5/R6: source pipelines sunk or spilled.
// R7/R10: global_load_lds one-shot blocks: 67-69 us (best). Duty-cycle capped
//   ~4 TB/s by vmcnt(0)+turnover per tile. R8: 81. R9: 99.
// Copy calibration: 6.29 TB/s at the SAME 1:1 r/w mix -> ~43 us floor.
// R11: flat-asm register pipeline CRASHED (GPU abort; suspect: ~64 live VGPR
//   at the (256,8) cap with asm-invisible vmcnt ops).
// R12 (this): same theory, crash class removed:
//   - buffer_load/store via SRSRC (T8): bounds-checked -> OOB reads 0 / OOB
//     stores dropped; faults impossible; bugs -> absmax, not abort.
//   - 2 VMEM/row (center f4 + broadcast dwordx2 halo for wave-edge lanes;
//     interior halo via __shfl) -> liveness ~48 VGPR, no spill pressure.
//   - row offset in SGPR soffset -> scalar address math.
//   - counted waits (NEVER 0): r=0 vmcnt(2), steady vmcnt(3), last vmcnt(1);
//     sched_barrier(0) after each wait (rule 18).
// Canaries: WRITE_SIZE must be exactly 131072 KB (spill canary), VGPR 48-64.
// Pre-commit: 65-72 us clean -> ROOFLINE next round.

#define B_ROWS 8192
#define C_CH   4096
#define NR     8
#define ROWB   (C_CH * 4)     // 16384 bytes per row

typedef unsigned int u32;
typedef u32 u32x4 __attribute__((ext_vector_type(4)));
typedef float f4 __attribute__((ext_vector_type(4)));
typedef float f2 __attribute__((ext_vector_type(2)));

__device__ __forceinline__ u32x4 make_srd(const void* p, u32 bytes) {
    union { const void* p; u32 w[2]; } u; u.p = p;
    u32x4 d; d.x = u.w[0]; d.y = u.w[1]; d.z = bytes; d.w = 0x00020000u;
    return d;
}
__device__ __forceinline__ f4 bl4(u32x4 s, u32 voff, u32 soff) {
    f4 r;
    asm volatile("buffer_load_dwordx4 %0, %1, %2, %3 offen"
                 : "=&v"(r) : "v"(voff), "s"(s), "s"(soff) : "memory");
    return r;
}
__device__ __forceinline__ f2 bl2(u32x4 s, u32 voff, u32 soff) {
    f2 r;
    asm volatile("buffer_load_dwordx2 %0, %1, %2, %3 offen"
                 : "=&v"(r) : "v"(voff), "s"(s), "s"(soff) : "memory");
    return r;
}
__device__ __forceinline__ void bs4(u32x4 s, u32 voff, u32 soff, f4 v) {
    asm volatile("buffer_store_dwordx4 %0, %1, %2, %3 offen"
                 :: "v"(v), "v"(voff), "s"(s), "s"(soff) : "memory");
}

__global__ __launch_bounds__(256, 8) void grouped_linear_kernel(
    const float* __restrict__ x, const float* __restrict__ W,
    const float* __restrict__ bias, float* __restrict__ out)
{
    const int tid   = threadIdx.x;
    const int chunk = (blockIdx.x << 8) + tid;   // 0..1023
    const int c     = chunk << 2;
    const int lane  = tid & 63;
    const int r0    = blockIdx.y * NR;

    // --- loop-invariant: W rows c..c+3 (20 contiguous floats) + bias ---
    const float4* W4 = (const float4*)(W + (size_t)c * 5);
    const float4 w0 = W4[0];  // W[c][0..3]
    const float4 w1 = W4[1];  // W[c][4], W[c+1][0..2]
    const float4 w2 = W4[2];  // W[c+1][3..4], W[c+2][0..1]
    const float4 w3 = W4[3];  // W[c+2][2..4], W[c+3][0]
    const float4 w4 = W4[4];  // W[c+3][1..4]
    const float4 bv = ((const float4*)bias)[chunk];

    const u32x4 sx = make_srd(x,   (u32)B_ROWS * ROWB);
    const u32x4 so = make_srd(out, (u32)B_ROWS * ROWB);

    // center voffset (per-lane, loop-invariant); row offset rides in soffset.
    const u32 cvoff = (u32)chunk * 16u;
    // halo: lane 63 reads next chunk's .x/.y (voff+16); every other lane reads
    // the wave-lane0 left-halo address (broadcast, 1-2 lines); lane 0 uses it.
    // chunk 0 row 0: underflow -> OOB -> returns 0 (bounds check = free pad).
    const u32 hvoff = (lane == 63) ? (cvoff + 16u)
                                   : (u32)((int)cvoff - lane * 16 - 8);
    const u32 sbase = (u32)r0 * (u32)ROWB;

    const bool has_m = (chunk > 0);
    const bool has_p = (chunk < 1023);

    // rolling distance-1 pipeline, parity-indexed (compile-time after unroll)
    f4 bc[2]; f2 hb[2];
    bc[0] = bl4(sx, cvoff, sbase);
    hb[0] = bl2(sx, hvoff, sbase);

    #pragma unroll
    for (int r = 0; r < NR; ++r) {
        const int cur = r & 1;
        // issue next row's loads BEFORE waiting on current row's
        if (r + 1 < NR) {
            const u32 snext = sbase + (u32)(r + 1) * ROWB;
            bc[cur ^ 1] = bl4(sx, cvoff, snext);
            hb[cur ^ 1] = bl2(sx, hvoff, snext);
        }
        // counted wait: younger = Lc/Lh(r+1) + S(r-1); never 0
        if (r == 0)           asm volatile("s_waitcnt vmcnt(2)" ::: "memory");
        else if (r == NR - 1) asm volatile("s_waitcnt vmcnt(1)" ::: "memory");
        else                  asm volatile("s_waitcnt vmcnt(3)" ::: "memory");
        __builtin_amdgcn_sched_barrier(0);   // rule 18: pin compute below wait

        const f4 xc = bc[cur];
        const f2 hl = hb[cur];

        // interior halo via cross-lane
        const float mz = __shfl_up(xc.z, 1);
        const float mw = __shfl_up(xc.w, 1);
        const float px = __shfl_down(xc.x, 1);
        const float py = __shfl_down(xc.y, 1);

        // win[m] = x[r, c - 2 + m], m = 0..7
        const float win0 = has_m ? (lane == 0  ? hl.x : mz) : 0.f;
        const float win1 = has_m ? (lane == 0  ? hl.y : mw) : 0.f;
        const float win2 = xc.x, win3 = xc.y, win4 = xc.z, win5 = xc.w;
        const float win6 = has_p ? (lane == 63 ? hl.x : px) : 0.f;
        const float win7 = has_p ? (lane == 63 ? hl.y : py) : 0.f;

        f4 o;
        o.x = fmaf(w0.x, win0, fmaf(w0.y, win1, fmaf(w0.z, win2, fmaf(w0.w, win3, fmaf(w1.x, win4, bv.x)))));
        o.y = fmaf(w1.y, win1, fmaf(w1.z, win2, fmaf(w1.w, win3, fmaf(w2.x, win4, fmaf(w2.y, win5, bv.y)))));
        o.z = fmaf(w2.z, win2, fmaf(w2.w, win3, fmaf(w3.x, win4, fmaf(w3.y, win5, fmaf(w3.z, win6, bv.z)))));
        o.w = fmaf(w3.w, win3, fmaf(w4.x, win4, fmaf(w4.y, win5, fmaf(w4.z, win6, fmaf(w4.w, win7, bv.w)))));

        bs4(so, cvoff, sbase + (u32)r * ROWB, o);
    }
}

extern "C" void kernel_launch(void* const* d_in, const int* in_sizes, int n_in,
                              void* d_out, int out_size, void* d_ws, size_t ws_size,
                              hipStream_t stream) {
    const float* x    = (const float*)d_in[0];
    const float* W    = (const float*)d_in[1];
    const float* bias = (const float*)d_in[2];
    float* out = (float*)d_out;

    dim3 grid(C_CH / 4 / 256, B_ROWS / NR);   // (4, 1024) = 4096 blocks
    dim3 block(256);
    grouped_linear_kernel<<<grid, block, 0, stream>>>(x, W, bias, out);
}

// Round 11
// 236.249 us; speedup vs baseline: 1.0090x; 1.0090x over previous
//
#include <hip/hip_runtime.h>

// out[r, i] = sum_{k=0..4} W[i,k] * x[r, i+k-2] + b[i], zero-padded at edges.
// B=8192 rows, C=4096 channels, K=5, fp32.
//
// R1-R4: compiler-scheduled loads, best ~76 us (loads sunk below stores).
// R5/R6: source register pipelines sunk or spilled by compiler.
// R7/R10: global_load_lds one-shot blocks: 67-69 us (BEST so far).
// R8: 81 (drain-0 dbuf). R9: 99 (counted vmcnt but TLP collapsed).
// R11: flat-asm pipeline crashed (fault). R12: buffer-asm pipeline ran (80 us)
//   but VGPR=28 proved the compiler DEMOTED W (plain loads re-issued in-loop,
//   conservative drains around opaque asm) -> schedule defeated again.
// R13 (this): the completion of the rule: EVERY VMEM op is volatile asm,
//   including W/bias setup loads. Volatile asm can't be rematerialized (W
//   pinned in registers) or reordered vs other volatile asm (counts exact),
//   and with ZERO plain VMEM the waitcnt pass inserts nothing.
//   Rolling distance-1 register pipeline, 2 VMEM/row (center f4 + broadcast
//   f2 halo; interior halo via shfl), counted waits never 0:
//   r=0 vmcnt(2), steady vmcnt(3), last vmcnt(1); sched_barrier(0) after.
//   Buffer ops bounds-checked (OOB read=0 / store dropped) -> no fault class;
//   OOB-returns-0 doubles as free zero-padding at row edges.
// Canaries: VGPR 48-60 (if <40 -> W demoted, method dead); WRITE exactly
//   131072 KB; FETCH ~67 MB.
// Pre-commit: 64-72 us with clean canaries -> all families plateau -> ROOFLINE.

#define B_ROWS 8192
#define C_CH   4096
#define NR     8
#define ROWB   (C_CH * 4)     // 16384 bytes per row

typedef unsigned int u32;
typedef u32 u32x4 __attribute__((ext_vector_type(4)));
typedef float f4 __attribute__((ext_vector_type(4)));
typedef float f2 __attribute__((ext_vector_type(2)));

__device__ __forceinline__ u32x4 make_srd(const void* p, u32 bytes) {
    union { const void* p; u32 w[2]; } u; u.p = p;
    u32x4 d; d.x = u.w[0]; d.y = u.w[1]; d.z = bytes; d.w = 0x00020000u;
    return d;
}
__device__ __forceinline__ f4 bl4(u32x4 s, u32 voff, u32 soff) {
    f4 r;
    asm volatile("buffer_load_dwordx4 %0, %1, %2, %3 offen"
                 : "=&v"(r) : "v"(voff), "s"(s), "s"(soff) : "memory");
    return r;
}
__device__ __forceinline__ f2 bl2(u32x4 s, u32 voff, u32 soff) {
    f2 r;
    asm volatile("buffer_load_dwordx2 %0, %1, %2, %3 offen"
                 : "=&v"(r) : "v"(voff), "s"(s), "s"(soff) : "memory");
    return r;
}
__device__ __forceinline__ void bs4(u32x4 s, u32 voff, u32 soff, f4 v) {
    asm volatile("buffer_store_dwordx4 %0, %1, %2, %3 offen"
                 :: "v"(v), "v"(voff), "s"(s), "s"(soff) : "memory");
}

__global__ __launch_bounds__(256, 8) void grouped_linear_kernel(
    const float* __restrict__ x, const float* __restrict__ W,
    const float* __restrict__ bias, float* __restrict__ out)
{
    const int tid   = threadIdx.x;
    const int chunk = (blockIdx.x << 8) + tid;   // 0..1023
    const int lane  = tid & 63;
    const int r0    = blockIdx.y * NR;

    const u32x4 sx = make_srd(x,    (u32)B_ROWS * ROWB);
    const u32x4 so = make_srd(out,  (u32)B_ROWS * ROWB);
    const u32x4 sw = make_srd(W,    (u32)C_CH * 5u * 4u);   // 81920 B
    const u32x4 sb = make_srd(bias, (u32)C_CH * 4u);        // 16384 B

    // ---- loop-invariant W rows c..c+3 (20 floats) + bias, ALL via asm ----
    // (pinned as asm outputs: cannot be demoted/rematerialized like R12)
    const u32 wvoff = (u32)chunk * 80u;
    const f4 w0 = bl4(sw, wvoff +  0u, 0u);  // W[c][0..3]
    const f4 w1 = bl4(sw, wvoff + 16u, 0u);  // W[c][4], W[c+1][0..2]
    const f4 w2 = bl4(sw, wvoff + 32u, 0u);  // W[c+1][3..4], W[c+2][0..1]
    const f4 w3 = bl4(sw, wvoff + 48u, 0u);  // W[c+2][2..4], W[c+3][0]
    const f4 w4 = bl4(sw, wvoff + 64u, 0u);  // W[c+3][1..4]
    const f4 bv = bl4(sb, (u32)chunk * 16u, 0u);

    // center voffset (per-lane, loop-invariant); row offset rides in soffset.
    const u32 cvoff = (u32)chunk * 16u;
    // halo: lane 63 reads next chunk's .x/.y; all other lanes read the wave's
    // left-halo address (broadcast); lane 0 consumes it. Block/array edges go
    // OOB -> bounds check returns 0 (free zero-pad); has_m/has_p guard values.
    const u32 hvoff = (lane == 63) ? (cvoff + 16u)
                                   : (u32)((int)cvoff - lane * 16 - 8);
    const u32 sbase = (u32)r0 * (u32)ROWB;

    const bool has_m = (chunk > 0);
    const bool has_p = (chunk < 1023);

    // rolling distance-1 pipeline, parity-indexed (compile-time after unroll)
    f4 bc[2]; f2 hb[2];
    bc[0] = bl4(sx, cvoff, sbase);
    hb[0] = bl2(sx, hvoff, sbase);

    #pragma unroll
    for (int r = 0; r < NR; ++r) {
        const int cur = r & 1;
        // issue next row's loads BEFORE waiting on current row's
        if (r + 1 < NR) {
            const u32 snext = sbase + (u32)(r + 1) * ROWB;
            bc[cur ^ 1] = bl4(sx, cvoff, snext);
            hb[cur ^ 1] = bl2(sx, hvoff, snext);
        }
        // counted wait: younger = Lc/Lh(r+1) + S(r-1); never 0.
        // (r==0 wait also covers the six W/bias loads - they are older.)
        if (r == 0)           asm volatile("s_waitcnt vmcnt(2)" ::: "memory");
        else if (r == NR - 1) asm volatile("s_waitcnt vmcnt(1)" ::: "memory");
        else                  asm volatile("s_waitcnt vmcnt(3)" ::: "memory");
        __builtin_amdgcn_sched_barrier(0);   // rule 18: pin compute below wait

        const f4 xc = bc[cur];
        const f2 hl = hb[cur];

        // interior halo via cross-lane
        const float mz = __shfl_up(xc.z, 1);
        const float mw = __shfl_up(xc.w, 1);
        const float px = __shfl_down(xc.x, 1);
        const float py = __shfl_down(xc.y, 1);

        // win[m] = x[r, c - 2 + m], m = 0..7
        const float win0 = has_m ? (lane == 0  ? hl.x : mz) : 0.f;
        const float win1 = has_m ? (lane == 0  ? hl.y : mw) : 0.f;
        const float win2 = xc.x, win3 = xc.y, win4 = xc.z, win5 = xc.w;
        const float win6 = has_p ? (lane == 63 ? hl.x : px) : 0.f;
        const float win7 = has_p ? (lane == 63 ? hl.y : py) : 0.f;

        f4 o;
        o.x = fmaf(w0.x, win0, fmaf(w0.y, win1, fmaf(w0.z, win2, fmaf(w0.w, win3, fmaf(w1.x, win4, bv.x)))));
        o.y = fmaf(w1.y, win1, fmaf(w1.z, win2, fmaf(w1.w, win3, fmaf(w2.x, win4, fmaf(w2.y, win5, bv.y)))));
        o.z = fmaf(w2.z, win2, fmaf(w2.w, win3, fmaf(w3.x, win4, fmaf(w3.y, win5, fmaf(w3.z, win6, bv.z)))));
        o.w = fmaf(w3.w, win3, fmaf(w4.x, win4, fmaf(w4.y, win5, fmaf(w4.z, win6, fmaf(w4.w, win7, bv.w)))));

        bs4(so, cvoff, sbase + (u32)r * ROWB, o);
    }
}

extern "C" void kernel_launch(void* const* d_in, const int* in_sizes, int n_in,
                              void* d_out, int out_size, void* d_ws, size_t ws_size,
                              hipStream_t stream) {
    const float* x    = (const float*)d_in[0];
    const float* W    = (const float*)d_in[1];
    const float* bias = (const float*)d_in[2];
    float* out = (float*)d_out;

    dim3 grid(C_CH / 4 / 256, B_ROWS / NR);   // (4, 1024) = 4096 blocks
    dim3 block(256);
    grouped_linear_kernel<<<grid, block, 0, stream>>>(x, W, bias, out);
}